// Round 6
// baseline (86169.348 us; speedup 1.0000x reference)
//
#include <hip/hip_runtime.h>

#define EPS_LN 1e-5f

static constexpr int Bn  = 64;
static constexpr int Sn  = 512;
static constexpr int Hn  = 512;
static constexpr int G4n = 2048;

typedef unsigned int uint32;
typedef _Float16 h2v __attribute__((ext_vector_type(2)));

__device__ __forceinline__ float sigf(float x)     { return 1.0f / (1.0f + __expf(-x)); }
__device__ __forceinline__ float tanhfast(float x) { return 1.0f - 2.0f / (1.0f + __expf(2.0f * x)); }

// dot2: acc += w.lo*h.lo + w.hi*h.hi   (f16 inputs, fp32 accumulate)
__device__ __forceinline__ float dot2h(uint32 w, uint32 h, float acc) {
#if defined(__has_builtin)
#if __has_builtin(__builtin_amdgcn_fdot2)
  return __builtin_amdgcn_fdot2(__builtin_bit_cast(h2v, w), __builtin_bit_cast(h2v, h), acc, false);
#define DOT2_DONE 1
#endif
#endif
#ifndef DOT2_DONE
  h2v wv = __builtin_bit_cast(h2v, w);
  h2v hv = __builtin_bit_cast(h2v, h);
  return acc + (float)wv.x * (float)hv.x + (float)wv.y * (float)hv.y;
#endif
}
__device__ __forceinline__ uint32 packh2(float a, float b) {
  h2v v; v.x = (_Float16)a; v.y = (_Float16)b;
  return __builtin_bit_cast(uint32, v);
}

// ---- block reductions (256-thread kernels) ----
__device__ __forceinline__ float blk_sum(float v, float* sm, int tid) {
#pragma unroll
  for (int o = 32; o; o >>= 1) v += __shfl_down(v, o, 64);
  __syncthreads();
  if ((tid & 63) == 0) sm[tid >> 6] = v;
  __syncthreads();
  return sm[0] + sm[1] + sm[2] + sm[3];
}
__device__ __forceinline__ float blk_max(float v, float* sm, int tid) {
#pragma unroll
  for (int o = 32; o; o >>= 1) v = fmaxf(v, __shfl_down(v, o, 64));
  __syncthreads();
  if ((tid & 63) == 0) sm[tid >> 6] = v;
  __syncthreads();
  return fmaxf(fmaxf(sm[0], sm[1]), fmaxf(sm[2], sm[3]));
}

// ---- fused (sum, sumsq) reduction across a 512-thread (8-wave) block ----
__device__ __forceinline__ void blk_sum2_w8(float& v1, float& v2, float* sm, int tid) {
#pragma unroll
  for (int o = 32; o; o >>= 1) {
    v1 += __shfl_down(v1, o, 64);
    v2 += __shfl_down(v2, o, 64);
  }
  __syncthreads();
  if ((tid & 63) == 0) { sm[(tid >> 6)*2] = v1; sm[(tid >> 6)*2 + 1] = v2; }
  __syncthreads();
  float r1 = 0.f, r2 = 0.f;
#pragma unroll
  for (int w = 0; w < 8; ++w) { r1 += sm[w*2]; r2 += sm[w*2+1]; }
  v1 = r1; v2 = r2;
}

// ---- Wh pack: WhP[l][kp][n] = half2(Wh[l][n][2kp], Wh[l][n][2kp+1]) ----
__global__ __launch_bounds__(256) void wh_pack_k(
    const float* __restrict__ Wh, uint32* __restrict__ WhP)
{
  __shared__ float tile[32][33];
  const int l = blockIdx.z;
  const int k0 = blockIdx.x * 32;
  const int n0 = blockIdx.y * 32;
  const int row = threadIdx.x >> 5, col = threadIdx.x & 31;
  const float* src = Wh + (long)l * G4n * Hn;
  uint32* dst = WhP + (long)l * 256 * G4n;
#pragma unroll
  for (int rr = 0; rr < 4; ++rr) {
    int nn = row + rr * 8;
    tile[nn][col] = src[(long)(n0 + nn) * Hn + k0 + col];
  }
  __syncthreads();
#pragma unroll
  for (int rr = 0; rr < 2; ++rr) {
    int kpl = row + rr * 8;                     // 0..15
    int kp = (k0 >> 1) + kpl;
    dst[(long)kp * G4n + n0 + col] = packh2(tile[col][2*kpl], tile[col][2*kpl+1]);
  }
}

__global__ void init_flags_k(int* flags) { flags[threadIdx.x] = 0; }

// ---- generic GEMM: C[M,N] = A[M,K] @ Bw[N,K]^T + bias[N]; tiles 128x128 ----
__global__ __launch_bounds__(256) void gemm_bias_k(
    const float* __restrict__ A, long lda,
    const float* __restrict__ Bw,
    const float* __restrict__ bias,
    float* __restrict__ C, long ldc, int K)
{
  __shared__ float As[16][128];
  __shared__ float Bs[16][128];
  const int tid = threadIdx.x;
  const long m0 = (long)blockIdx.y * 128;
  const long n0 = (long)blockIdx.x * 128;
  const int tx = tid & 15, ty = tid >> 4;
  const int lrow = tid >> 1;
  const int lc0  = (tid & 1) * 8;
  float acc[8][8];
#pragma unroll
  for (int i = 0; i < 8; ++i)
#pragma unroll
    for (int j = 0; j < 8; ++j) acc[i][j] = 0.f;

  const float* Arow = A + (m0 + lrow) * lda;
  const float* Brow = Bw + (n0 + lrow) * (long)K;

  for (int k0 = 0; k0 < K; k0 += 16) {
    float4 a0 = *(const float4*)(Arow + k0 + lc0);
    float4 a1 = *(const float4*)(Arow + k0 + lc0 + 4);
    float4 b0 = *(const float4*)(Brow + k0 + lc0);
    float4 b1 = *(const float4*)(Brow + k0 + lc0 + 4);
    __syncthreads();
    As[lc0+0][lrow]=a0.x; As[lc0+1][lrow]=a0.y; As[lc0+2][lrow]=a0.z; As[lc0+3][lrow]=a0.w;
    As[lc0+4][lrow]=a1.x; As[lc0+5][lrow]=a1.y; As[lc0+6][lrow]=a1.z; As[lc0+7][lrow]=a1.w;
    Bs[lc0+0][lrow]=b0.x; Bs[lc0+1][lrow]=b0.y; Bs[lc0+2][lrow]=b0.z; Bs[lc0+3][lrow]=b0.w;
    Bs[lc0+4][lrow]=b1.x; Bs[lc0+5][lrow]=b1.y; Bs[lc0+6][lrow]=b1.z; Bs[lc0+7][lrow]=b1.w;
    __syncthreads();
#pragma unroll
    for (int kk = 0; kk < 16; ++kk) {
      float av[8], bv[8];
      *(float4*)&av[0] = *(const float4*)&As[kk][ty*8];
      *(float4*)&av[4] = *(const float4*)&As[kk][ty*8+4];
      *(float4*)&bv[0] = *(const float4*)&Bs[kk][tx*8];
      *(float4*)&bv[4] = *(const float4*)&Bs[kk][tx*8+4];
#pragma unroll
      for (int i = 0; i < 8; ++i)
#pragma unroll
        for (int j = 0; j < 8; ++j) acc[i][j] += av[i] * bv[j];
    }
  }
#pragma unroll
  for (int i = 0; i < 8; ++i) {
    long m = m0 + ty*8 + i;
    float* crow = C + m * ldc + n0 + tx*8;
    const float* br = bias + n0 + tx*8;
    float4 o0, o1;
    o0.x = acc[i][0]+br[0]; o0.y = acc[i][1]+br[1]; o0.z = acc[i][2]+br[2]; o0.w = acc[i][3]+br[3];
    o1.x = acc[i][4]+br[4]; o1.y = acc[i][5]+br[5]; o1.z = acc[i][6]+br[6]; o1.w = acc[i][7]+br[7];
    *(float4*)crow = o0; *(float4*)(crow+4) = o1;
  }
}

// ---- ip-chunk GEMM, time-major output: out row r = t_local*64 + b ----
__global__ __launch_bounds__(256) void gemm_ip_k(
    const float* __restrict__ A,       // [B,S,H]
    const float* __restrict__ Bw,      // [2048,512]
    const float* __restrict__ bias,
    float* __restrict__ C,             // [TCH*64, 2048]
    int s0)
{
  __shared__ float As[16][128];
  __shared__ float Bs[16][128];
  const int tid = threadIdx.x;
  const long m0 = (long)blockIdx.y * 128;
  const long n0 = (long)blockIdx.x * 128;
  const int tx = tid & 15, ty = tid >> 4;
  const int lrow = tid >> 1;
  const int lc0  = (tid & 1) * 8;
  float acc[8][8];
#pragma unroll
  for (int i = 0; i < 8; ++i)
#pragma unroll
    for (int j = 0; j < 8; ++j) acc[i][j] = 0.f;

  const long r  = m0 + lrow;
  const long b  = r & 63;
  const long sl = r >> 6;
  const float* Arow = A + (b * Sn + s0 + sl) * Hn;
  const float* Brow = Bw + (n0 + lrow) * 512L;

  for (int k0 = 0; k0 < 512; k0 += 16) {
    float4 a0 = *(const float4*)(Arow + k0 + lc0);
    float4 a1 = *(const float4*)(Arow + k0 + lc0 + 4);
    float4 b0 = *(const float4*)(Brow + k0 + lc0);
    float4 b1 = *(const float4*)(Brow + k0 + lc0 + 4);
    __syncthreads();
    As[lc0+0][lrow]=a0.x; As[lc0+1][lrow]=a0.y; As[lc0+2][lrow]=a0.z; As[lc0+3][lrow]=a0.w;
    As[lc0+4][lrow]=a1.x; As[lc0+5][lrow]=a1.y; As[lc0+6][lrow]=a1.z; As[lc0+7][lrow]=a1.w;
    Bs[lc0+0][lrow]=b0.x; Bs[lc0+1][lrow]=b0.y; Bs[lc0+2][lrow]=b0.z; Bs[lc0+3][lrow]=b0.w;
    Bs[lc0+4][lrow]=b1.x; Bs[lc0+5][lrow]=b1.y; Bs[lc0+6][lrow]=b1.z; Bs[lc0+7][lrow]=b1.w;
    __syncthreads();
#pragma unroll
    for (int kk = 0; kk < 16; ++kk) {
      float av[8], bv[8];
      *(float4*)&av[0] = *(const float4*)&As[kk][ty*8];
      *(float4*)&av[4] = *(const float4*)&As[kk][ty*8+4];
      *(float4*)&bv[0] = *(const float4*)&Bs[kk][tx*8];
      *(float4*)&bv[4] = *(const float4*)&Bs[kk][tx*8+4];
#pragma unroll
      for (int i = 0; i < 8; ++i)
#pragma unroll
        for (int j = 0; j < 8; ++j) acc[i][j] += av[i] * bv[j];
    }
  }
#pragma unroll
  for (int i = 0; i < 8; ++i) {
    long m = m0 + ty*8 + i;
    float* crow = C + m * 2048L + n0 + tx*8;
    const float* br = bias + n0 + tx*8;
    float4 o0, o1;
    o0.x = acc[i][0]+br[0]; o0.y = acc[i][1]+br[1]; o0.z = acc[i][2]+br[2]; o0.w = acc[i][3]+br[3];
    o1.x = acc[i][4]+br[4]; o1.y = acc[i][5]+br[5]; o1.z = acc[i][6]+br[6]; o1.w = acc[i][7]+br[7];
    *(float4*)crow = o0; *(float4*)(crow+4) = o1;
  }
}

// ---- M=64 GEMM (used for q projection) ----
__global__ __launch_bounds__(256) void gemm_m64_k(
    const float* __restrict__ A, long lda,
    const float* __restrict__ Bw,
    const float* __restrict__ bias,
    float* __restrict__ P,
    int N, int K)
{
  __shared__ float As[64][64];
  __shared__ float Bs[64][64];
  const int tid = threadIdx.x;
  const int n0 = blockIdx.x * 64;
  const int kc = blockIdx.y;
  const int Kc = K / gridDim.y;
  const int tx = tid & 15, ty = tid >> 4;
  const int row = tid >> 2, q = tid & 3;
  float acc[4][4];
#pragma unroll
  for (int i = 0; i < 4; ++i)
#pragma unroll
    for (int j = 0; j < 4; ++j) acc[i][j] = 0.f;

  for (int k0 = kc * Kc; k0 < kc * Kc + Kc; k0 += 64) {
    float4 a[4], b[4];
#pragma unroll
    for (int c = 0; c < 4; ++c) {
      a[c] = *(const float4*)(A  + (long)row * lda       + k0 + q*16 + c*4);
      b[c] = *(const float4*)(Bw + (long)(n0 + row) * K  + k0 + q*16 + c*4);
    }
    __syncthreads();
#pragma unroll
    for (int c = 0; c < 4; ++c) {
      int kb = q*16 + c*4;
      As[kb+0][row]=a[c].x; As[kb+1][row]=a[c].y; As[kb+2][row]=a[c].z; As[kb+3][row]=a[c].w;
      Bs[kb+0][row]=b[c].x; Bs[kb+1][row]=b[c].y; Bs[kb+2][row]=b[c].z; Bs[kb+3][row]=b[c].w;
    }
    __syncthreads();
#pragma unroll
    for (int kk = 0; kk < 64; ++kk) {
      float4 av = *(const float4*)&As[kk][ty*4];
      float4 bv = *(const float4*)&Bs[kk][tx*4];
      float am[4] = {av.x, av.y, av.z, av.w};
      float bm[4] = {bv.x, bv.y, bv.z, bv.w};
#pragma unroll
      for (int i = 0; i < 4; ++i)
#pragma unroll
        for (int j = 0; j < 4; ++j) acc[i][j] += am[i] * bm[j];
    }
  }
#pragma unroll
  for (int i = 0; i < 4; ++i) {
    int m = ty*4 + i;
    float* pr = P + ((long)kc * 64 + m) * N + n0 + tx*4;
#pragma unroll
    for (int j = 0; j < 4; ++j) {
      float bb = bias ? bias[n0 + tx*4 + j] : 0.f;
      pr[j] = acc[i][j] + bb;
    }
  }
}

// ---- persistent LSTM recurrence, 4-way k-split across 256 blocks ----
// blk: b = blk&63 (batch), kq = blk>>6 (k-quarter; stride-64 partners share XCD
// under %8 round-robin). 512 threads; thread owns gates j4=tid*4 and unit tid.
// Per step: partial GEMV over k in [kq*128, kq*128+128) -> pz (parity dbuf)
// -> flag (monotonic global step) -> spin on 3 partners -> sum partials ->
// LN1/gates/c/LN2/h computed redundantly in every block (h,c in LDS).
__global__ __launch_bounds__(512, 4) void lstm_seq4_k(
    const uint32* __restrict__ WhP,   // [256 kp][2048 n] this layer (f16 pairs)
    const float* __restrict__ bh,
    const float* __restrict__ ipc,    // [TCH*64][2048] time-major LN'd input proj
    const float* __restrict__ g_hid, const float* __restrict__ b_hid,
    const float* __restrict__ g_cell, const float* __restrict__ b_cell,
    float* __restrict__ hst, float* __restrict__ cst,  // [64][512]
    float* __restrict__ hseq,         // [B,S,H]
    float* __restrict__ pz,           // [2][4][64][2048] fp32 partials
    int* __restrict__ flags,          // [4][64]
    int t0, int nsteps, int gbase)    // gbase: global step index of ts=0 (>=1)
{
  const int blk = blockIdx.x;
  const int b   = blk & 63;
  const int kq  = blk >> 6;
  const int tid = threadIdx.x;
  const int j4  = tid * 4;
  __shared__ __align__(16) float hlds[512];
  __shared__ __align__(16) float clds[512];
  __shared__ __align__(16) float gates[2048];
  __shared__ __align__(16) uint32 hh[64];   // packed h for OUR k-slice
  __shared__ float sm[16];

  hlds[tid] = hst[b*512 + tid];
  clds[tid] = cst[b*512 + tid];
  __syncthreads();
  if (tid < 64) hh[tid] = packh2(hlds[kq*128 + 2*tid], hlds[kq*128 + 2*tid + 1]);

  const float4 bhv   = *(const float4*)(bh    + j4);
  const float4 ghv   = *(const float4*)(g_hid + j4);
  const float4 bhidv = *(const float4*)(b_hid + j4);
  const float gcv = g_cell[tid];
  const float bcv = b_cell[tid];
  const uint32* wp = WhP + (long)(kq * 64) * 2048 + j4;
  __syncthreads();

  for (int ts = 0; ts < nsteps; ++ts) {
    const int gstep = gbase + ts;
    const long gp = (long)(gstep & 1) * 524288;   // parity buffer offset (floats)
    float4 ipv = *(const float4*)(ipc + ((long)ts * 64 + b) * 2048 + j4);

    // partial GEMV over our 128-k slice (64 half2 pairs)
    float a0 = 0.f, a1 = 0.f, a2 = 0.f, a3 = 0.f;
#pragma unroll 4
    for (int kp = 0; kp < 64; kp += 2) {
      uint2 hpair = *(const uint2*)(hh + kp);
      uint4 w0 = *(const uint4*)(wp + (long)kp * 2048);
      uint4 w1 = *(const uint4*)(wp + (long)(kp + 1) * 2048);
      a0 = dot2h(w0.x, hpair.x, a0); a1 = dot2h(w0.y, hpair.x, a1);
      a2 = dot2h(w0.z, hpair.x, a2); a3 = dot2h(w0.w, hpair.x, a3);
      a0 = dot2h(w1.x, hpair.y, a0); a1 = dot2h(w1.y, hpair.y, a1);
      a2 = dot2h(w1.z, hpair.y, a2); a3 = dot2h(w1.w, hpair.y, a3);
    }
    float4 st; st.x = a0; st.y = a1; st.z = a2; st.w = a3;
    *(float4*)(pz + gp + (long)(kq*64 + b)*2048 + j4) = st;
    __threadfence();              // release our partials
    __syncthreads();
    if (tid == 0) atomicExch(flags + kq*64 + b, gstep);
    if (tid < 4 && tid != kq) {
      while (atomicAdd(flags + tid*64 + b, 0) < gstep) { __builtin_amdgcn_s_sleep(2); }
    }
    __syncthreads();
    __threadfence();              // acquire partners' partials

    float z0 = bhv.x, z1 = bhv.y, z2 = bhv.z, z3 = bhv.w;
#pragma unroll
    for (int q = 0; q < 4; ++q) {
      float4 pq = *(const float4*)(pz + gp + (long)(q*64 + b)*2048 + j4);
      z0 += pq.x; z1 += pq.y; z2 += pq.z; z3 += pq.w;
    }
    // LN1 over 2048
    float s1 = z0 + z1 + z2 + z3;
    float s2 = z0*z0 + z1*z1 + z2*z2 + z3*z3;
    blk_sum2_w8(s1, s2, sm, tid);
    const float m1 = s1 * (1.f/2048.f);
    const float r1 = rsqrtf(s2 * (1.f/2048.f) - m1*m1 + EPS_LN);
    gates[j4+0] = ipv.x + (z0 - m1) * r1 * ghv.x + bhidv.x;
    gates[j4+1] = ipv.y + (z1 - m1) * r1 * ghv.y + bhidv.y;
    gates[j4+2] = ipv.z + (z2 - m1) * r1 * ghv.z + bhidv.z;
    gates[j4+3] = ipv.w + (z3 - m1) * r1 * ghv.w + bhidv.w;
    __syncthreads();
    // c/h update: unit j = tid
    const float iv = gates[tid];
    const float fv = gates[512 + tid];
    const float gv = gates[1024 + tid];
    const float ov = gates[1536 + tid];
    const float cc = sigf(fv) * clds[tid] + sigf(iv) * tanhfast(gv);
    clds[tid] = cc;
    float t1 = cc, t2 = cc * cc;
    blk_sum2_w8(t1, t2, sm, tid);
    const float m2 = t1 * (1.f/512.f);
    const float r2 = rsqrtf(t2 * (1.f/512.f) - m2*m2 + EPS_LN);
    const float lc = (cc - m2) * r2 * gcv + bcv;
    const float h = sigf(ov) * tanhfast(lc);
    hlds[tid] = h;
    if (kq == 0) hseq[((long)b * Sn + t0 + ts) * Hn + tid] = h;
    __syncthreads();
    if (tid < 64) hh[tid] = packh2(hlds[kq*128 + 2*tid], hlds[kq*128 + 2*tid + 1]);
    __syncthreads();
  }
  if (kq == 0) { hst[b*512 + tid] = hlds[tid]; cst[b*512 + tid] = clds[tid]; }
}

// ---- layernorm over rows of 2048 (in-place) ----
__global__ __launch_bounds__(256) void ln_rows_k(
    float* __restrict__ X, const float* __restrict__ g, const float* __restrict__ bt)
{
  const long row = blockIdx.x;
  float* xr = X + row * 2048L;
  const int tid = threadIdx.x;
  __shared__ float sm[4];
  float4 v0 = *(float4*)(xr + tid*8);
  float4 v1 = *(float4*)(xr + tid*8 + 4);
  float s1 = v0.x+v0.y+v0.z+v0.w + v1.x+v1.y+v1.z+v1.w;
  float s2 = v0.x*v0.x+v0.y*v0.y+v0.z*v0.z+v0.w*v0.w
           + v1.x*v1.x+v1.y*v1.y+v1.z*v1.z+v1.w*v1.w;
  s1 = blk_sum(s1, sm, tid);
  s2 = blk_sum(s2, sm, tid);
  const float mean = s1 * (1.f/2048.f);
  const float rstd = rsqrtf(s2 * (1.f/2048.f) - mean*mean + EPS_LN);
  const int base = tid*8;
  float vals[8] = {v0.x,v0.y,v0.z,v0.w,v1.x,v1.y,v1.z,v1.w};
#pragma unroll
  for (int c = 0; c < 8; ++c)
    xr[base + c] = (vals[c] - mean) * rstd * g[base + c] + bt[base + c];
}

// ---- highway combine (elementwise), optional residual skip ----
__global__ __launch_bounds__(256) void highway_ew_k(
    const float* __restrict__ T1, const float* __restrict__ T2, const float* __restrict__ T3,
    const float* __restrict__ hs, float* __restrict__ seq, int skip)
{
  long i = ((long)blockIdx.x * 256 + threadIdx.x) * 4;
  float4 t1 = *(const float4*)(T1 + i);
  float4 t2 = *(const float4*)(T2 + i);
  float4 t3 = *(const float4*)(T3 + i);
  float4 hv = *(const float4*)(hs + i);
  float4 sv;
  if (skip) sv = *(const float4*)(seq + i); else { sv.x=0; sv.y=0; sv.z=0; sv.w=0; }
  float4 o;
  o.x = sigf(t1.x) * fmaxf(t3.x, 0.f) + sigf(t2.x) * hv.x + sv.x;
  o.y = sigf(t1.y) * fmaxf(t3.y, 0.f) + sigf(t2.y) * hv.y + sv.y;
  o.z = sigf(t1.z) * fmaxf(t3.z, 0.f) + sigf(t2.z) * hv.z + sv.z;
  o.w = sigf(t1.w) * fmaxf(t3.w, 0.f) + sigf(t2.w) * hv.w + sv.w;
  *(float4*)(seq + i) = o;
}

__global__ void init_hc_k(float* h, float* c)
{
  int i = blockIdx.x * 256 + threadIdx.x;
  h[i] = 0.f; c[i] = 0.f;
}

// ---- qkh[b][hd][:] = sum_{j in head} q[b, hd*64+j] * Wk[hd*64+j, :]; qbk = q.bk ----
__global__ __launch_bounds__(256) void qkh_k(
    const float* __restrict__ qlst, const float* __restrict__ Wk,
    const float* __restrict__ bk,
    float* __restrict__ qkh, float* __restrict__ qbk)
{
  const int hd = blockIdx.x, cg = blockIdx.y;
  const int b = threadIdx.x & 63, sc = threadIdx.x >> 6;
  const int col0 = cg * 128 + sc * 32;
  float qreg[64];
  const float* qp = qlst + b*512 + hd*64;
#pragma unroll
  for (int j4 = 0; j4 < 16; ++j4) {
    float4 v = *(const float4*)(qp + j4*4);
    qreg[j4*4+0]=v.x; qreg[j4*4+1]=v.y; qreg[j4*4+2]=v.z; qreg[j4*4+3]=v.w;
  }
  float acc[32];
#pragma unroll
  for (int c = 0; c < 32; ++c) acc[c] = 0.f;
  for (int j = 0; j < 64; ++j) {
    float qv = qreg[j];
    const float* wr = Wk + (long)(hd*64 + j)*512 + col0;
#pragma unroll
    for (int c4 = 0; c4 < 8; ++c4) {
      float4 w = *(const float4*)(wr + c4*4);
      acc[c4*4+0] = __builtin_fmaf(qv, w.x, acc[c4*4+0]);
      acc[c4*4+1] = __builtin_fmaf(qv, w.y, acc[c4*4+1]);
      acc[c4*4+2] = __builtin_fmaf(qv, w.z, acc[c4*4+2]);
      acc[c4*4+3] = __builtin_fmaf(qv, w.w, acc[c4*4+3]);
    }
  }
  float* op = qkh + ((long)b*8 + hd)*512 + col0;
#pragma unroll
  for (int c4 = 0; c4 < 8; ++c4) {
    float4 o;
    o.x = acc[c4*4+0]; o.y = acc[c4*4+1]; o.z = acc[c4*4+2]; o.w = acc[c4*4+3];
    *(float4*)(op + c4*4) = o;
  }
  if (cg == 0 && sc == 0) {
    float s = 0.f;
    for (int j = 0; j < 64; ++j) s += qreg[j] * bk[hd*64 + j];
    qbk[b*8 + hd] = s;
  }
}

// ---- fused last-row attention ----
__global__ __launch_bounds__(256) void attn2_k(
    const float* __restrict__ seq,   // [B,S,H]
    const float* __restrict__ qkh,   // [64][8][512]
    const float* __restrict__ qbk,   // [64][8]
    float* __restrict__ u)           // [64][8][512]
{
  const int b = blockIdx.x, hd = blockIdx.y, tid = threadIdx.x;
  __shared__ __align__(16) float qk[512];
  __shared__ float p[512];
  __shared__ float sm[4];
  qk[tid]       = qkh[((long)b*8 + hd)*512 + tid];
  qk[tid + 256] = qkh[((long)b*8 + hd)*512 + tid + 256];
  __syncthreads();
  const float bias = qbk[b*8 + hd];

  float loc[2]; float mx = -3.0e38f;
#pragma unroll
  for (int v = 0; v < 2; ++v) {
    int s = tid + v*256;
    const float4* sr = (const float4*)(seq + ((long)b*512 + s)*512);
    const float4* qv4 = (const float4*)qk;
    float d = 0.f;
    for (int k4 = 0; k4 < 128; ++k4) {
      float4 sv = sr[k4], qv = qv4[k4];
      d += sv.x*qv.x + sv.y*qv.y + sv.z*qv.z + sv.w*qv.w;
    }
    d = (d + bias) * 0.125f;
    loc[v] = d; mx = fmaxf(mx, d);
  }
  const float M = blk_max(mx, sm, tid);
  float sum = 0.f;
#pragma unroll
  for (int v = 0; v < 2; ++v) {
    int s = tid + v*256;
    float e = __expf(loc[v] - M);
    p[s] = e; sum += e;
  }
  const float SM = blk_sum(sum, sm, tid);
  const float inv = 1.f / SM;

  float u0 = 0.f, u1 = 0.f;
  for (int s = 0; s < 512; ++s) {
    float ps = p[s];
    const float* srow = seq + ((long)b*512 + s)*512;
    u0 = __builtin_fmaf(ps, srow[tid], u0);
    u1 = __builtin_fmaf(ps, srow[tid + 256], u1);
  }
  u[((long)b*8 + hd)*512 + tid]       = u0 * inv;
  u[((long)b*8 + hd)*512 + tid + 256] = u1 * inv;
}

// ---- ctx[b][n] = u[b][hd(n)][:] . Wv[n][:] + bv[n] ----
__global__ __launch_bounds__(256) void ctxv_k(
    const float* __restrict__ u, const float* __restrict__ Wv,
    const float* __restrict__ bv, float* __restrict__ ctx)
{
  const int b = blockIdx.x, tid = threadIdx.x;
  __shared__ __align__(16) float ul[8*512];
  for (int i = tid; i < 4096; i += 256) ul[i] = u[(long)b*4096 + i];
  __syncthreads();
#pragma unroll
  for (int v = 0; v < 2; ++v) {
    int n = tid + v*256;
    int hd = n >> 6;
    const float4* wr = (const float4*)(Wv + (long)n*512);
    const float4* uv = (const float4*)&ul[hd*512];
    float acc = 0.f;
    for (int k4 = 0; k4 < 128; ++k4) {
      float4 w = wr[k4], x = uv[k4];
      acc += w.x*x.x + w.y*x.y + w.z*x.z + w.w*x.w;
    }
    ctx[b*512 + n] = acc + bv[n];
  }
}

// ---- output head ----
__global__ __launch_bounds__(256) void head_k(
    const float* __restrict__ ctx,
    const float* __restrict__ Wo, const float* __restrict__ bo,
    const float* __restrict__ seq,
    const float* __restrict__ att_g, const float* __restrict__ att_b,
    const float* __restrict__ on_g, const float* __restrict__ on_b,
    const float* __restrict__ Wp1, const float* __restrict__ bp1,
    const float* __restrict__ Wp2, const float* __restrict__ bp2,
    float* __restrict__ out)
{
  const int b = blockIdx.x, tid = threadIdx.x;
  __shared__ __align__(16) float cs[512];
  __shared__ __align__(16) float buf[512];
  __shared__ float sm[4];
  cs[tid]       = ctx[b*512 + tid];
  cs[tid + 256] = ctx[b*512 + tid + 256];
  __syncthreads();

  const float* srow = seq + ((long)b*512 + 511) * 512;
  float o[2];
#pragma unroll
  for (int v = 0; v < 2; ++v) {
    int j = tid + v*256;
    const float4* w4 = (const float4*)(Wo + (long)j * 512);
    const float4* c4 = (const float4*)cs;
    float acc = 0.f;
    for (int kx = 0; kx < 128; ++kx) {
      float4 w = w4[kx], c = c4[kx];
      acc += w.x*c.x + w.y*c.y + w.z*c.z + w.w*c.w;
    }
    o[v] = acc + bo[j] + srow[j];
  }
  float s1 = o[0] + o[1], s2 = o[0]*o[0] + o[1]*o[1];
  s1 = blk_sum(s1, sm, tid); s2 = blk_sum(s2, sm, tid);
  float m1 = s1 * (1.f/512.f);
  float r1 = rsqrtf(s2 * (1.f/512.f) - m1*m1 + EPS_LN);
  float a[2];
#pragma unroll
  for (int v = 0; v < 2; ++v) {
    int j = tid + v*256;
    a[v] = (o[v] - m1) * r1 * att_g[j] + att_b[j];
  }
  s1 = a[0] + a[1]; s2 = a[0]*a[0] + a[1]*a[1];
  s1 = blk_sum(s1, sm, tid); s2 = blk_sum(s2, sm, tid);
  float m2 = s1 * (1.f/512.f);
  float r2 = rsqrtf(s2 * (1.f/512.f) - m2*m2 + EPS_LN);
#pragma unroll
  for (int v = 0; v < 2; ++v) {
    int j = tid + v*256;
    buf[j] = (a[v] - m2) * r2 * on_g[j] + on_b[j];
  }
  __syncthreads();

  const float4* w1 = (const float4*)(Wp1 + (long)tid * 512);
  const float4* b4 = (const float4*)buf;
  float acc = 0.f;
  for (int kx = 0; kx < 128; ++kx) {
    float4 w = w1[kx], c = b4[kx];
    acc += w.x*c.x + w.y*c.y + w.z*c.z + w.w*c.w;
  }
  float mid = fmaxf(acc + bp1[tid], 0.f);
  float contrib = mid * Wp2[tid];
  float tot = blk_sum(contrib, sm, tid);
  if (tid == 0) out[b] = tot + bp2[0];
}

extern "C" void kernel_launch(void* const* d_in, const int* in_sizes, int n_in,
                              void* d_out, int out_size, void* d_ws, size_t ws_size,
                              hipStream_t stream)
{
  const float* x     = (const float*)d_in[0];
  const float* Wi    = (const float*)d_in[1];
  const float* bi    = (const float*)d_in[2];
  const float* Wh    = (const float*)d_in[3];
  const float* bh    = (const float*)d_in[4];
  const float* g_in  = (const float*)d_in[5];
  const float* b_in  = (const float*)d_in[6];
  const float* g_hid = (const float*)d_in[7];
  const float* b_hid = (const float*)d_in[8];
  const float* g_cell= (const float*)d_in[9];
  const float* b_cell= (const float*)d_in[10];
  const float* hwWt  = (const float*)d_in[11];
  const float* hwbt  = (const float*)d_in[12];
  const float* hwWc  = (const float*)d_in[13];
  const float* hwbc  = (const float*)d_in[14];
  const float* hwWh  = (const float*)d_in[15];
  const float* hwbh  = (const float*)d_in[16];
  const float* Wq    = (const float*)d_in[17];
  const float* bq    = (const float*)d_in[18];
  const float* Wk    = (const float*)d_in[19];
  const float* bk    = (const float*)d_in[20];
  const float* Wv    = (const float*)d_in[21];
  const float* bv    = (const float*)d_in[22];
  const float* Wo    = (const float*)d_in[23];
  const float* bo    = (const float*)d_in[24];
  const float* att_g = (const float*)d_in[25];
  const float* att_b = (const float*)d_in[26];
  const float* on_g  = (const float*)d_in[27];
  const float* on_b  = (const float*)d_in[28];
  const float* Wp1   = (const float*)d_in[29];
  const float* bp1   = (const float*)d_in[30];
  const float* Wp2   = (const float*)d_in[31];
  const float* bp2   = (const float*)d_in[32];
  float* out = (float*)d_out;

  // ---- workspace layout (floats); never touches d_in ----
  const long SEQF = (long)Bn * Sn * Hn;      // 16,777,216
  const long WHPF = 2L * 256 * G4n;          // 1,048,576 (uint32 slots)
  const long PZF  = 2L * 4 * 64 * 2048;      // 1,048,576
  const long wsF  = (long)(ws_size / 4);

  float* ws   = (float*)d_ws;
  float* seq  = ws;                  // [B,S,H]
  float* hseq = seq  + SEQF;         // [B,S,H]
  uint32* WhP = (uint32*)(hseq + SEQF);  // [2][256][2048] packed f16 pairs
  float* pz   = hseq + SEQF + WHPF;  // [2][4][64][2048] partials
  int*  flags = (int*)(pz + PZF);    // [4][64] (pad to 1024)
  float* hst  = pz + PZF + 1024L;    // [64][512]
  float* cst  = hst  + 32768L;
  float* qlst = cst  + 32768L;       // [64][512]
  float* ctx  = qlst + 32768L;       // [64][512]
  float* qkh  = ctx  + 32768L;       // [64][8][512]
  float* qbk  = qkh  + 262144L;      // [64][8] (pad to 1024)
  float* uat  = qbk  + 1024L;        // [64][8][512]
  float* ipc  = uat  + 262144L;      // [TCH*64][2048]
  const long baseF = (ipc - ws);

  int TCH = 128;
  while (TCH > 16 && baseF + (long)TCH * 64 * 2048 > wsF) TCH >>= 1;

  wh_pack_k<<<dim3(16, 64, 2), 256, 0, stream>>>(Wh, WhP);
  init_flags_k<<<1, 256, 0, stream>>>(flags);

  const int NCH = Sn / TCH;
  const int MROWS = TCH * 64;
  const int NMCH = (Bn * Sn) / MROWS;

  for (int l = 0; l < 2; ++l) {
    const float* seqin = (l == 0) ? x : seq;
    init_hc_k<<<128, 256, 0, stream>>>(hst, cst);
    for (int c = 0; c < NCH; ++c) {
      const int s0 = c * TCH;
      gemm_ip_k<<<dim3(16, TCH/2), 256, 0, stream>>>(seqin, Wi + (long)l*G4n*Hn, bi + l*G4n, ipc, s0);
      ln_rows_k<<<TCH*64, 256, 0, stream>>>(ipc, g_in + l*G4n, b_in + l*G4n);
      lstm_seq4_k<<<256, 512, 0, stream>>>(WhP + (long)l*256*G4n, bh + l*G4n, ipc,
          g_hid + l*G4n, b_hid + l*G4n, g_cell + l*Hn, b_cell + l*Hn,
          hst, cst, hseq, pz, flags, s0, TCH, l*Sn + s0 + 1);
    }
    // highway, chunked over M; T buffers live in the (dead) ipc region
    float* T1 = ipc;
    float* T2 = ipc + (long)MROWS * 512;
    float* T3 = ipc + 2L * MROWS * 512;
    for (int mc = 0; mc < NMCH; ++mc) {
      const long m0 = (long)mc * MROWS;
      gemm_bias_k<<<dim3(4, MROWS/128), 256, 0, stream>>>(hseq + m0*512, 512, hwWt + (long)l*Hn*Hn, hwbt + l*Hn, T1, 512, 512);
      gemm_bias_k<<<dim3(4, MROWS/128), 256, 0, stream>>>(hseq + m0*512, 512, hwWc + (long)l*Hn*Hn, hwbc + l*Hn, T2, 512, 512);
      gemm_bias_k<<<dim3(4, MROWS/128), 256, 0, stream>>>(hseq + m0*512, 512, hwWh + (long)l*Hn*Hn, hwbh + l*Hn, T3, 512, 512);
      highway_ew_k<<<(MROWS*512)/1024, 256, 0, stream>>>(T1, T2, T3, hseq + m0*512, seq + m0*512, (l == 0) ? 0 : 1);
    }
  }

  // attention on last query row, K/V never materialized
  gemm_m64_k<<<dim3(8, 1), 256, 0, stream>>>(seq + 511L*512, 512L*512, Wq, bq, qlst, 512, 512);
  qkh_k<<<dim3(8, 4), 256, 0, stream>>>(qlst, Wk, bk, qkh, qbk);
  attn2_k<<<dim3(64, 8), 256, 0, stream>>>(seq, qkh, qbk, uat);
  ctxv_k<<<64, 256, 0, stream>>>(uat, Wv, bv, ctx);
  head_k<<<64, 256, 0, stream>>>(ctx, Wo, bo, seq, att_g, att_b, on_g, on_b, Wp1, bp1, Wp2, bp2, out);
}

// Round 7
// 14247.792 us; speedup vs baseline: 6.0479x; 6.0479x over previous
//
#include <hip/hip_runtime.h>

#define EPS_LN 1e-5f

static constexpr int Bn  = 64;
static constexpr int Sn  = 512;
static constexpr int Hn  = 512;
static constexpr int G4n = 2048;

typedef unsigned int uint32;
typedef unsigned long long uint64;
typedef _Float16 h2v __attribute__((ext_vector_type(2)));

__device__ __forceinline__ float sigf(float x)     { return 1.0f / (1.0f + __expf(-x)); }
__device__ __forceinline__ float tanhfast(float x) { return 1.0f - 2.0f / (1.0f + __expf(2.0f * x)); }

// dot2: acc += w.lo*h.lo + w.hi*h.hi   (f16 inputs, fp32 accumulate)
__device__ __forceinline__ float dot2h(uint32 w, uint32 h, float acc) {
#if defined(__has_builtin)
#if __has_builtin(__builtin_amdgcn_fdot2)
  return __builtin_amdgcn_fdot2(__builtin_bit_cast(h2v, w), __builtin_bit_cast(h2v, h), acc, false);
#define DOT2_DONE 1
#endif
#endif
#ifndef DOT2_DONE
  h2v wv = __builtin_bit_cast(h2v, w);
  h2v hv = __builtin_bit_cast(h2v, h);
  return acc + (float)wv.x * (float)hv.x + (float)wv.y * (float)hv.y;
#endif
}
__device__ __forceinline__ uint32 packh2(float a, float b) {
  h2v v; v.x = (_Float16)a; v.y = (_Float16)b;
  return __builtin_bit_cast(uint32, v);
}
__device__ __forceinline__ uint64 packf2(float a, float b) {
  float2 v; v.x = a; v.y = b;
  return __builtin_bit_cast(uint64, v);
}

// ---- block reductions (256-thread kernels) ----
__device__ __forceinline__ float blk_sum(float v, float* sm, int tid) {
#pragma unroll
  for (int o = 32; o; o >>= 1) v += __shfl_down(v, o, 64);
  __syncthreads();
  if ((tid & 63) == 0) sm[tid >> 6] = v;
  __syncthreads();
  return sm[0] + sm[1] + sm[2] + sm[3];
}
__device__ __forceinline__ float blk_max(float v, float* sm, int tid) {
#pragma unroll
  for (int o = 32; o; o >>= 1) v = fmaxf(v, __shfl_down(v, o, 64));
  __syncthreads();
  if ((tid & 63) == 0) sm[tid >> 6] = v;
  __syncthreads();
  return fmaxf(fmaxf(sm[0], sm[1]), fmaxf(sm[2], sm[3]));
}

// ---- fused (sum, sumsq) reduction across a 512-thread (8-wave) block ----
__device__ __forceinline__ void blk_sum2_w8(float& v1, float& v2, float* sm, int tid) {
#pragma unroll
  for (int o = 32; o; o >>= 1) {
    v1 += __shfl_down(v1, o, 64);
    v2 += __shfl_down(v2, o, 64);
  }
  __syncthreads();
  if ((tid & 63) == 0) { sm[(tid >> 6)*2] = v1; sm[(tid >> 6)*2 + 1] = v2; }
  __syncthreads();
  float r1 = 0.f, r2 = 0.f;
#pragma unroll
  for (int w = 0; w < 8; ++w) { r1 += sm[w*2]; r2 += sm[w*2+1]; }
  v1 = r1; v2 = r2;
}

// ---- Wh pack: WhP[l][kp][n] = half2(Wh[l][n][2kp], Wh[l][n][2kp+1]) ----
__global__ __launch_bounds__(256) void wh_pack_k(
    const float* __restrict__ Wh, uint32* __restrict__ WhP)
{
  __shared__ float tile[32][33];
  const int l = blockIdx.z;
  const int k0 = blockIdx.x * 32;
  const int n0 = blockIdx.y * 32;
  const int row = threadIdx.x >> 5, col = threadIdx.x & 31;
  const float* src = Wh + (long)l * G4n * Hn;
  uint32* dst = WhP + (long)l * 256 * G4n;
#pragma unroll
  for (int rr = 0; rr < 4; ++rr) {
    int nn = row + rr * 8;
    tile[nn][col] = src[(long)(n0 + nn) * Hn + k0 + col];
  }
  __syncthreads();
#pragma unroll
  for (int rr = 0; rr < 2; ++rr) {
    int kpl = row + rr * 8;                     // 0..15
    int kp = (k0 >> 1) + kpl;
    dst[(long)kp * G4n + n0 + col] = packh2(tile[col][2*kpl], tile[col][2*kpl+1]);
  }
}

__global__ void init_flags_k(int* flags) { flags[threadIdx.x] = 0; }

// ---- generic GEMM: C[M,N] = A[M,K] @ Bw[N,K]^T + bias[N]; tiles 128x128 ----
__global__ __launch_bounds__(256) void gemm_bias_k(
    const float* __restrict__ A, long lda,
    const float* __restrict__ Bw,
    const float* __restrict__ bias,
    float* __restrict__ C, long ldc, int K)
{
  __shared__ float As[16][128];
  __shared__ float Bs[16][128];
  const int tid = threadIdx.x;
  const long m0 = (long)blockIdx.y * 128;
  const long n0 = (long)blockIdx.x * 128;
  const int tx = tid & 15, ty = tid >> 4;
  const int lrow = tid >> 1;
  const int lc0  = (tid & 1) * 8;
  float acc[8][8];
#pragma unroll
  for (int i = 0; i < 8; ++i)
#pragma unroll
    for (int j = 0; j < 8; ++j) acc[i][j] = 0.f;

  const float* Arow = A + (m0 + lrow) * lda;
  const float* Brow = Bw + (n0 + lrow) * (long)K;

  for (int k0 = 0; k0 < K; k0 += 16) {
    float4 a0 = *(const float4*)(Arow + k0 + lc0);
    float4 a1 = *(const float4*)(Arow + k0 + lc0 + 4);
    float4 b0 = *(const float4*)(Brow + k0 + lc0);
    float4 b1 = *(const float4*)(Brow + k0 + lc0 + 4);
    __syncthreads();
    As[lc0+0][lrow]=a0.x; As[lc0+1][lrow]=a0.y; As[lc0+2][lrow]=a0.z; As[lc0+3][lrow]=a0.w;
    As[lc0+4][lrow]=a1.x; As[lc0+5][lrow]=a1.y; As[lc0+6][lrow]=a1.z; As[lc0+7][lrow]=a1.w;
    Bs[lc0+0][lrow]=b0.x; Bs[lc0+1][lrow]=b0.y; Bs[lc0+2][lrow]=b0.z; Bs[lc0+3][lrow]=b0.w;
    Bs[lc0+4][lrow]=b1.x; Bs[lc0+5][lrow]=b1.y; Bs[lc0+6][lrow]=b1.z; Bs[lc0+7][lrow]=b1.w;
    __syncthreads();
#pragma unroll
    for (int kk = 0; kk < 16; ++kk) {
      float av[8], bv[8];
      *(float4*)&av[0] = *(const float4*)&As[kk][ty*8];
      *(float4*)&av[4] = *(const float4*)&As[kk][ty*8+4];
      *(float4*)&bv[0] = *(const float4*)&Bs[kk][tx*8];
      *(float4*)&bv[4] = *(const float4*)&Bs[kk][tx*8+4];
#pragma unroll
      for (int i = 0; i < 8; ++i)
#pragma unroll
        for (int j = 0; j < 8; ++j) acc[i][j] += av[i] * bv[j];
    }
  }
#pragma unroll
  for (int i = 0; i < 8; ++i) {
    long m = m0 + ty*8 + i;
    float* crow = C + m * ldc + n0 + tx*8;
    const float* br = bias + n0 + tx*8;
    float4 o0, o1;
    o0.x = acc[i][0]+br[0]; o0.y = acc[i][1]+br[1]; o0.z = acc[i][2]+br[2]; o0.w = acc[i][3]+br[3];
    o1.x = acc[i][4]+br[4]; o1.y = acc[i][5]+br[5]; o1.z = acc[i][6]+br[6]; o1.w = acc[i][7]+br[7];
    *(float4*)crow = o0; *(float4*)(crow+4) = o1;
  }
}

// ---- ip-chunk GEMM, time-major output: out row r = t_local*64 + b ----
__global__ __launch_bounds__(256) void gemm_ip_k(
    const float* __restrict__ A,       // [B,S,H]
    const float* __restrict__ Bw,      // [2048,512]
    const float* __restrict__ bias,
    float* __restrict__ C,             // [TCH*64, 2048]
    int s0)
{
  __shared__ float As[16][128];
  __shared__ float Bs[16][128];
  const int tid = threadIdx.x;
  const long m0 = (long)blockIdx.y * 128;
  const long n0 = (long)blockIdx.x * 128;
  const int tx = tid & 15, ty = tid >> 4;
  const int lrow = tid >> 1;
  const int lc0  = (tid & 1) * 8;
  float acc[8][8];
#pragma unroll
  for (int i = 0; i < 8; ++i)
#pragma unroll
    for (int j = 0; j < 8; ++j) acc[i][j] = 0.f;

  const long r  = m0 + lrow;
  const long b  = r & 63;
  const long sl = r >> 6;
  const float* Arow = A + (b * Sn + s0 + sl) * Hn;
  const float* Brow = Bw + (n0 + lrow) * 512L;

  for (int k0 = 0; k0 < 512; k0 += 16) {
    float4 a0 = *(const float4*)(Arow + k0 + lc0);
    float4 a1 = *(const float4*)(Arow + k0 + lc0 + 4);
    float4 b0 = *(const float4*)(Brow + k0 + lc0);
    float4 b1 = *(const float4*)(Brow + k0 + lc0 + 4);
    __syncthreads();
    As[lc0+0][lrow]=a0.x; As[lc0+1][lrow]=a0.y; As[lc0+2][lrow]=a0.z; As[lc0+3][lrow]=a0.w;
    As[lc0+4][lrow]=a1.x; As[lc0+5][lrow]=a1.y; As[lc0+6][lrow]=a1.z; As[lc0+7][lrow]=a1.w;
    Bs[lc0+0][lrow]=b0.x; Bs[lc0+1][lrow]=b0.y; Bs[lc0+2][lrow]=b0.z; Bs[lc0+3][lrow]=b0.w;
    Bs[lc0+4][lrow]=b1.x; Bs[lc0+5][lrow]=b1.y; Bs[lc0+6][lrow]=b1.z; Bs[lc0+7][lrow]=b1.w;
    __syncthreads();
#pragma unroll
    for (int kk = 0; kk < 16; ++kk) {
      float av[8], bv[8];
      *(float4*)&av[0] = *(const float4*)&As[kk][ty*8];
      *(float4*)&av[4] = *(const float4*)&As[kk][ty*8+4];
      *(float4*)&bv[0] = *(const float4*)&Bs[kk][tx*8];
      *(float4*)&bv[4] = *(const float4*)&Bs[kk][tx*8+4];
#pragma unroll
      for (int i = 0; i < 8; ++i)
#pragma unroll
        for (int j = 0; j < 8; ++j) acc[i][j] += av[i] * bv[j];
    }
  }
#pragma unroll
  for (int i = 0; i < 8; ++i) {
    long m = m0 + ty*8 + i;
    float* crow = C + m * 2048L + n0 + tx*8;
    const float* br = bias + n0 + tx*8;
    float4 o0, o1;
    o0.x = acc[i][0]+br[0]; o0.y = acc[i][1]+br[1]; o0.z = acc[i][2]+br[2]; o0.w = acc[i][3]+br[3];
    o1.x = acc[i][4]+br[4]; o1.y = acc[i][5]+br[5]; o1.z = acc[i][6]+br[6]; o1.w = acc[i][7]+br[7];
    *(float4*)crow = o0; *(float4*)(crow+4) = o1;
  }
}

// ---- M=64 GEMM (used for q projection) ----
__global__ __launch_bounds__(256) void gemm_m64_k(
    const float* __restrict__ A, long lda,
    const float* __restrict__ Bw,
    const float* __restrict__ bias,
    float* __restrict__ P,
    int N, int K)
{
  __shared__ float As[64][64];
  __shared__ float Bs[64][64];
  const int tid = threadIdx.x;
  const int n0 = blockIdx.x * 64;
  const int kc = blockIdx.y;
  const int Kc = K / gridDim.y;
  const int tx = tid & 15, ty = tid >> 4;
  const int row = tid >> 2, q = tid & 3;
  float acc[4][4];
#pragma unroll
  for (int i = 0; i < 4; ++i)
#pragma unroll
    for (int j = 0; j < 4; ++j) acc[i][j] = 0.f;

  for (int k0 = kc * Kc; k0 < kc * Kc + Kc; k0 += 64) {
    float4 a[4], b[4];
#pragma unroll
    for (int c = 0; c < 4; ++c) {
      a[c] = *(const float4*)(A  + (long)row * lda       + k0 + q*16 + c*4);
      b[c] = *(const float4*)(Bw + (long)(n0 + row) * K  + k0 + q*16 + c*4);
    }
    __syncthreads();
#pragma unroll
    for (int c = 0; c < 4; ++c) {
      int kb = q*16 + c*4;
      As[kb+0][row]=a[c].x; As[kb+1][row]=a[c].y; As[kb+2][row]=a[c].z; As[kb+3][row]=a[c].w;
      Bs[kb+0][row]=b[c].x; Bs[kb+1][row]=b[c].y; Bs[kb+2][row]=b[c].z; Bs[kb+3][row]=b[c].w;
    }
    __syncthreads();
#pragma unroll
    for (int kk = 0; kk < 64; ++kk) {
      float4 av = *(const float4*)&As[kk][ty*4];
      float4 bv = *(const float4*)&Bs[kk][tx*4];
      float am[4] = {av.x, av.y, av.z, av.w};
      float bm[4] = {bv.x, bv.y, bv.z, bv.w};
#pragma unroll
      for (int i = 0; i < 4; ++i)
#pragma unroll
        for (int j = 0; j < 4; ++j) acc[i][j] += am[i] * bm[j];
    }
  }
#pragma unroll
  for (int i = 0; i < 4; ++i) {
    int m = ty*4 + i;
    float* pr = P + ((long)kc * 64 + m) * N + n0 + tx*4;
#pragma unroll
    for (int j = 0; j < 4; ++j) {
      float bb = bias ? bias[n0 + tx*4 + j] : 0.f;
      pr[j] = acc[i][j] + bb;
    }
  }
}

// ---- persistent LSTM recurrence, 2-way k-split across 128 blocks ----
// blk: b = blk&63 (batch), kh = blk>>6 (k-half; partners blk, blk+64 share XCD
// under %8 round-robin). 512 threads; thread owns gates j4=tid*4 and unit tid.
// Exchange via RELAXED AGENT-SCOPE ATOMICS only (no fences -> no L2 flush):
// payload atomic stores -> __syncthreads (s_waitcnt vmcnt(0)) -> flag store;
// partner spins on flag, then atomic-loads payload.
__global__ __launch_bounds__(512, 4) void lstm_seq2_k(
    const uint32* __restrict__ WhP,   // [256 kp][2048 n] this layer (f16 pairs)
    const float* __restrict__ bh,
    const float* __restrict__ ipc,    // [TCH*64][2048] time-major LN'd input proj
    const float* __restrict__ g_hid, const float* __restrict__ b_hid,
    const float* __restrict__ g_cell, const float* __restrict__ b_cell,
    float* __restrict__ hst, float* __restrict__ cst,  // [64][512]
    float* __restrict__ hseq,         // [B,S,H]
    float* __restrict__ pz,           // [2 parity][2 kh][64 b][2048] fp32 partials
    int* __restrict__ flags,          // [2 kh][64 b]
    int t0, int nsteps, int gbase)    // gbase >= 1, monotonic over the launch
{
  const int blk = blockIdx.x;
  const int b   = blk & 63;
  const int kh  = blk >> 6;
  const int tid = threadIdx.x;
  const int j4  = tid * 4;
  __shared__ __align__(16) float hlds[512];
  __shared__ __align__(16) float clds[512];
  __shared__ __align__(16) float gates[2048];
  __shared__ __align__(16) uint32 hh[128];   // packed h for OUR k-half
  __shared__ float sm[16];

  hlds[tid] = hst[b*512 + tid];
  clds[tid] = cst[b*512 + tid];
  __syncthreads();
  if (tid < 128) hh[tid] = packh2(hlds[kh*256 + 2*tid], hlds[kh*256 + 2*tid + 1]);

  const float4 bhv   = *(const float4*)(bh    + j4);
  const float4 ghv   = *(const float4*)(g_hid + j4);
  const float4 bhidv = *(const float4*)(b_hid + j4);
  const float gcv = g_cell[tid];
  const float bcv = b_cell[tid];
  const uint32* wp = WhP + (long)(kh * 128) * 2048 + j4;
  int* myflag   = flags + kh*64 + b;
  int* partflag = flags + (kh^1)*64 + b;
  __syncthreads();

  for (int ts = 0; ts < nsteps; ++ts) {
    const int gstep = gbase + ts;
    const long gp = (long)(gstep & 1) * 262144;   // parity buffer offset (floats)
    float4 ipv = *(const float4*)(ipc + ((long)ts * 64 + b) * 2048 + j4);

    // partial GEMV over our 256-k slice (128 half2 pairs)
    float a0 = 0.f, a1 = 0.f, a2 = 0.f, a3 = 0.f;
#pragma unroll 4
    for (int kp = 0; kp < 128; kp += 2) {
      uint2 hpair = *(const uint2*)(hh + kp);
      uint4 w0 = *(const uint4*)(wp + (long)kp * 2048);
      uint4 w1 = *(const uint4*)(wp + (long)(kp + 1) * 2048);
      a0 = dot2h(w0.x, hpair.x, a0); a1 = dot2h(w0.y, hpair.x, a1);
      a2 = dot2h(w0.z, hpair.x, a2); a3 = dot2h(w0.w, hpair.x, a3);
      a0 = dot2h(w1.x, hpair.y, a0); a1 = dot2h(w1.y, hpair.y, a1);
      a2 = dot2h(w1.z, hpair.y, a2); a3 = dot2h(w1.w, hpair.y, a3);
    }
    // publish partials via relaxed agent atomics (bypass caches, no fence)
    uint64* myp = (uint64*)(pz + gp + (long)(kh*64 + b)*2048 + j4);
    __hip_atomic_store(myp,     packf2(a0, a1), __ATOMIC_RELAXED, __HIP_MEMORY_SCOPE_AGENT);
    __hip_atomic_store(myp + 1, packf2(a2, a3), __ATOMIC_RELAXED, __HIP_MEMORY_SCOPE_AGENT);
    __syncthreads();              // s_waitcnt vmcnt(0) before barrier => stores visible
    if (tid == 0) __hip_atomic_store(myflag, gstep, __ATOMIC_RELAXED, __HIP_MEMORY_SCOPE_AGENT);
    if (tid == 0) {
      while (__hip_atomic_load(partflag, __ATOMIC_RELAXED, __HIP_MEMORY_SCOPE_AGENT) < gstep) {
        __builtin_amdgcn_s_sleep(4);
      }
    }
    __syncthreads();

    // read partner partials (atomic loads: coherent, no cache invalidation)
    const uint64* pp = (const uint64*)(pz + gp + (long)((kh^1)*64 + b)*2048 + j4);
    uint64 q01 = __hip_atomic_load(pp,     __ATOMIC_RELAXED, __HIP_MEMORY_SCOPE_AGENT);
    uint64 q23 = __hip_atomic_load(pp + 1, __ATOMIC_RELAXED, __HIP_MEMORY_SCOPE_AGENT);
    float2 f01 = __builtin_bit_cast(float2, q01);
    float2 f23 = __builtin_bit_cast(float2, q23);
    float z0 = a0 + f01.x + bhv.x;
    float z1 = a1 + f01.y + bhv.y;
    float z2 = a2 + f23.x + bhv.z;
    float z3 = a3 + f23.y + bhv.w;

    // LN1 over 2048
    float s1 = z0 + z1 + z2 + z3;
    float s2 = z0*z0 + z1*z1 + z2*z2 + z3*z3;
    blk_sum2_w8(s1, s2, sm, tid);
    const float m1 = s1 * (1.f/2048.f);
    const float r1 = rsqrtf(s2 * (1.f/2048.f) - m1*m1 + EPS_LN);
    gates[j4+0] = ipv.x + (z0 - m1) * r1 * ghv.x + bhidv.x;
    gates[j4+1] = ipv.y + (z1 - m1) * r1 * ghv.y + bhidv.y;
    gates[j4+2] = ipv.z + (z2 - m1) * r1 * ghv.z + bhidv.z;
    gates[j4+3] = ipv.w + (z3 - m1) * r1 * ghv.w + bhidv.w;
    __syncthreads();

    // c/h update: unit j = tid (redundant in both partner blocks)
    const float iv = gates[tid];
    const float fv = gates[512 + tid];
    const float gv = gates[1024 + tid];
    const float ov = gates[1536 + tid];
    const float cc = sigf(fv) * clds[tid] + sigf(iv) * tanhfast(gv);
    clds[tid] = cc;
    float t1 = cc, t2 = cc * cc;
    blk_sum2_w8(t1, t2, sm, tid);
    const float m2 = t1 * (1.f/512.f);
    const float r2 = rsqrtf(t2 * (1.f/512.f) - m2*m2 + EPS_LN);
    const float lc = (cc - m2) * r2 * gcv + bcv;
    const float h = sigf(ov) * tanhfast(lc);
    hlds[tid] = h;
    if (kh == 0) hseq[((long)b * Sn + t0 + ts) * Hn + tid] = h;
    __syncthreads();
    if (tid < 128) hh[tid] = packh2(hlds[kh*256 + 2*tid], hlds[kh*256 + 2*tid + 1]);
    __syncthreads();
  }
  if (kh == 0) { hst[b*512 + tid] = hlds[tid]; cst[b*512 + tid] = clds[tid]; }
}

// ---- layernorm over rows of 2048 (in-place) ----
__global__ __launch_bounds__(256) void ln_rows_k(
    float* __restrict__ X, const float* __restrict__ g, const float* __restrict__ bt)
{
  const long row = blockIdx.x;
  float* xr = X + row * 2048L;
  const int tid = threadIdx.x;
  __shared__ float sm[4];
  float4 v0 = *(float4*)(xr + tid*8);
  float4 v1 = *(float4*)(xr + tid*8 + 4);
  float s1 = v0.x+v0.y+v0.z+v0.w + v1.x+v1.y+v1.z+v1.w;
  float s2 = v0.x*v0.x+v0.y*v0.y+v0.z*v0.z+v0.w*v0.w
           + v1.x*v1.x+v1.y*v1.y+v1.z*v1.z+v1.w*v1.w;
  s1 = blk_sum(s1, sm, tid);
  s2 = blk_sum(s2, sm, tid);
  const float mean = s1 * (1.f/2048.f);
  const float rstd = rsqrtf(s2 * (1.f/2048.f) - mean*mean + EPS_LN);
  const int base = tid*8;
  float vals[8] = {v0.x,v0.y,v0.z,v0.w,v1.x,v1.y,v1.z,v1.w};
#pragma unroll
  for (int c = 0; c < 8; ++c)
    xr[base + c] = (vals[c] - mean) * rstd * g[base + c] + bt[base + c];
}

// ---- highway combine (elementwise), optional residual skip ----
__global__ __launch_bounds__(256) void highway_ew_k(
    const float* __restrict__ T1, const float* __restrict__ T2, const float* __restrict__ T3,
    const float* __restrict__ hs, float* __restrict__ seq, int skip)
{
  long i = ((long)blockIdx.x * 256 + threadIdx.x) * 4;
  float4 t1 = *(const float4*)(T1 + i);
  float4 t2 = *(const float4*)(T2 + i);
  float4 t3 = *(const float4*)(T3 + i);
  float4 hv = *(const float4*)(hs + i);
  float4 sv;
  if (skip) sv = *(const float4*)(seq + i); else { sv.x=0; sv.y=0; sv.z=0; sv.w=0; }
  float4 o;
  o.x = sigf(t1.x) * fmaxf(t3.x, 0.f) + sigf(t2.x) * hv.x + sv.x;
  o.y = sigf(t1.y) * fmaxf(t3.y, 0.f) + sigf(t2.y) * hv.y + sv.y;
  o.z = sigf(t1.z) * fmaxf(t3.z, 0.f) + sigf(t2.z) * hv.z + sv.z;
  o.w = sigf(t1.w) * fmaxf(t3.w, 0.f) + sigf(t2.w) * hv.w + sv.w;
  *(float4*)(seq + i) = o;
}

__global__ void init_hc_k(float* h, float* c)
{
  int i = blockIdx.x * 256 + threadIdx.x;
  h[i] = 0.f; c[i] = 0.f;
}

// ---- qkh[b][hd][:] = sum_{j in head} q[b, hd*64+j] * Wk[hd*64+j, :]; qbk = q.bk ----
__global__ __launch_bounds__(256) void qkh_k(
    const float* __restrict__ qlst, const float* __restrict__ Wk,
    const float* __restrict__ bk,
    float* __restrict__ qkh, float* __restrict__ qbk)
{
  const int hd = blockIdx.x, cg = blockIdx.y;
  const int b = threadIdx.x & 63, sc = threadIdx.x >> 6;
  const int col0 = cg * 128 + sc * 32;
  float qreg[64];
  const float* qp = qlst + b*512 + hd*64;
#pragma unroll
  for (int j4 = 0; j4 < 16; ++j4) {
    float4 v = *(const float4*)(qp + j4*4);
    qreg[j4*4+0]=v.x; qreg[j4*4+1]=v.y; qreg[j4*4+2]=v.z; qreg[j4*4+3]=v.w;
  }
  float acc[32];
#pragma unroll
  for (int c = 0; c < 32; ++c) acc[c] = 0.f;
  for (int j = 0; j < 64; ++j) {
    float qv = qreg[j];
    const float* wr = Wk + (long)(hd*64 + j)*512 + col0;
#pragma unroll
    for (int c4 = 0; c4 < 8; ++c4) {
      float4 w = *(const float4*)(wr + c4*4);
      acc[c4*4+0] = __builtin_fmaf(qv, w.x, acc[c4*4+0]);
      acc[c4*4+1] = __builtin_fmaf(qv, w.y, acc[c4*4+1]);
      acc[c4*4+2] = __builtin_fmaf(qv, w.z, acc[c4*4+2]);
      acc[c4*4+3] = __builtin_fmaf(qv, w.w, acc[c4*4+3]);
    }
  }
  float* op = qkh + ((long)b*8 + hd)*512 + col0;
#pragma unroll
  for (int c4 = 0; c4 < 8; ++c4) {
    float4 o;
    o.x = acc[c4*4+0]; o.y = acc[c4*4+1]; o.z = acc[c4*4+2]; o.w = acc[c4*4+3];
    *(float4*)(op + c4*4) = o;
  }
  if (cg == 0 && sc == 0) {
    float s = 0.f;
    for (int j = 0; j < 64; ++j) s += qreg[j] * bk[hd*64 + j];
    qbk[b*8 + hd] = s;
  }
}

// ---- fused last-row attention ----
__global__ __launch_bounds__(256) void attn2_k(
    const float* __restrict__ seq,   // [B,S,H]
    const float* __restrict__ qkh,   // [64][8][512]
    const float* __restrict__ qbk,   // [64][8]
    float* __restrict__ u)           // [64][8][512]
{
  const int b = blockIdx.x, hd = blockIdx.y, tid = threadIdx.x;
  __shared__ __align__(16) float qk[512];
  __shared__ float p[512];
  __shared__ float sm[4];
  qk[tid]       = qkh[((long)b*8 + hd)*512 + tid];
  qk[tid + 256] = qkh[((long)b*8 + hd)*512 + tid + 256];
  __syncthreads();
  const float bias = qbk[b*8 + hd];

  float loc[2]; float mx = -3.0e38f;
#pragma unroll
  for (int v = 0; v < 2; ++v) {
    int s = tid + v*256;
    const float4* sr = (const float4*)(seq + ((long)b*512 + s)*512);
    const float4* qv4 = (const float4*)qk;
    float d = 0.f;
    for (int k4 = 0; k4 < 128; ++k4) {
      float4 sv = sr[k4], qv = qv4[k4];
      d += sv.x*qv.x + sv.y*qv.y + sv.z*qv.z + sv.w*qv.w;
    }
    d = (d + bias) * 0.125f;
    loc[v] = d; mx = fmaxf(mx, d);
  }
  const float M = blk_max(mx, sm, tid);
  float sum = 0.f;
#pragma unroll
  for (int v = 0; v < 2; ++v) {
    int s = tid + v*256;
    float e = __expf(loc[v] - M);
    p[s] = e; sum += e;
  }
  const float SM = blk_sum(sum, sm, tid);
  const float inv = 1.f / SM;

  float u0 = 0.f, u1 = 0.f;
  for (int s = 0; s < 512; ++s) {
    float ps = p[s];
    const float* srow = seq + ((long)b*512 + s)*512;
    u0 = __builtin_fmaf(ps, srow[tid], u0);
    u1 = __builtin_fmaf(ps, srow[tid + 256], u1);
  }
  u[((long)b*8 + hd)*512 + tid]       = u0 * inv;
  u[((long)b*8 + hd)*512 + tid + 256] = u1 * inv;
}

// ---- ctx[b][n] = u[b][hd(n)][:] . Wv[n][:] + bv[n] ----
__global__ __launch_bounds__(256) void ctxv_k(
    const float* __restrict__ u, const float* __restrict__ Wv,
    const float* __restrict__ bv, float* __restrict__ ctx)
{
  const int b = blockIdx.x, tid = threadIdx.x;
  __shared__ __align__(16) float ul[8*512];
  for (int i = tid; i < 4096; i += 256) ul[i] = u[(long)b*4096 + i];
  __syncthreads();
#pragma unroll
  for (int v = 0; v < 2; ++v) {
    int n = tid + v*256;
    int hd = n >> 6;
    const float4* wr = (const float4*)(Wv + (long)n*512);
    const float4* uv = (const float4*)&ul[hd*512];
    float acc = 0.f;
    for (int k4 = 0; k4 < 128; ++k4) {
      float4 w = wr[k4], x = uv[k4];
      acc += w.x*x.x + w.y*x.y + w.z*x.z + w.w*x.w;
    }
    ctx[b*512 + n] = acc + bv[n];
  }
}

// ---- output head ----
__global__ __launch_bounds__(256) void head_k(
    const float* __restrict__ ctx,
    const float* __restrict__ Wo, const float* __restrict__ bo,
    const float* __restrict__ seq,
    const float* __restrict__ att_g, const float* __restrict__ att_b,
    const float* __restrict__ on_g, const float* __restrict__ on_b,
    const float* __restrict__ Wp1, const float* __restrict__ bp1,
    const float* __restrict__ Wp2, const float* __restrict__ bp2,
    float* __restrict__ out)
{
  const int b = blockIdx.x, tid = threadIdx.x;
  __shared__ __align__(16) float cs[512];
  __shared__ __align__(16) float buf[512];
  __shared__ float sm[4];
  cs[tid]       = ctx[b*512 + tid];
  cs[tid + 256] = ctx[b*512 + tid + 256];
  __syncthreads();

  const float* srow = seq + ((long)b*512 + 511) * 512;
  float o[2];
#pragma unroll
  for (int v = 0; v < 2; ++v) {
    int j = tid + v*256;
    const float4* w4 = (const float4*)(Wo + (long)j * 512);
    const float4* c4 = (const float4*)cs;
    float acc = 0.f;
    for (int kx = 0; kx < 128; ++kx) {
      float4 w = w4[kx], c = c4[kx];
      acc += w.x*c.x + w.y*c.y + w.z*c.z + w.w*c.w;
    }
    o[v] = acc + bo[j] + srow[j];
  }
  float s1 = o[0] + o[1], s2 = o[0]*o[0] + o[1]*o[1];
  s1 = blk_sum(s1, sm, tid); s2 = blk_sum(s2, sm, tid);
  float m1 = s1 * (1.f/512.f);
  float r1 = rsqrtf(s2 * (1.f/512.f) - m1*m1 + EPS_LN);
  float a[2];
#pragma unroll
  for (int v = 0; v < 2; ++v) {
    int j = tid + v*256;
    a[v] = (o[v] - m1) * r1 * att_g[j] + att_b[j];
  }
  s1 = a[0] + a[1]; s2 = a[0]*a[0] + a[1]*a[1];
  s1 = blk_sum(s1, sm, tid); s2 = blk_sum(s2, sm, tid);
  float m2 = s1 * (1.f/512.f);
  float r2 = rsqrtf(s2 * (1.f/512.f) - m2*m2 + EPS_LN);
#pragma unroll
  for (int v = 0; v < 2; ++v) {
    int j = tid + v*256;
    buf[j] = (a[v] - m2) * r2 * on_g[j] + on_b[j];
  }
  __syncthreads();

  const float4* w1 = (const float4*)(Wp1 + (long)tid * 512);
  const float4* b4 = (const float4*)buf;
  float acc = 0.f;
  for (int kx = 0; kx < 128; ++kx) {
    float4 w = w1[kx], c = b4[kx];
    acc += w.x*c.x + w.y*c.y + w.z*c.z + w.w*c.w;
  }
  float mid = fmaxf(acc + bp1[tid], 0.f);
  float contrib = mid * Wp2[tid];
  float tot = blk_sum(contrib, sm, tid);
  if (tid == 0) out[b] = tot + bp2[0];
}

extern "C" void kernel_launch(void* const* d_in, const int* in_sizes, int n_in,
                              void* d_out, int out_size, void* d_ws, size_t ws_size,
                              hipStream_t stream)
{
  const float* x     = (const float*)d_in[0];
  const float* Wi    = (const float*)d_in[1];
  const float* bi    = (const float*)d_in[2];
  const float* Wh    = (const float*)d_in[3];
  const float* bh    = (const float*)d_in[4];
  const float* g_in  = (const float*)d_in[5];
  const float* b_in  = (const float*)d_in[6];
  const float* g_hid = (const float*)d_in[7];
  const float* b_hid = (const float*)d_in[8];
  const float* g_cell= (const float*)d_in[9];
  const float* b_cell= (const float*)d_in[10];
  const float* hwWt  = (const float*)d_in[11];
  const float* hwbt  = (const float*)d_in[12];
  const float* hwWc  = (const float*)d_in[13];
  const float* hwbc  = (const float*)d_in[14];
  const float* hwWh  = (const float*)d_in[15];
  const float* hwbh  = (const float*)d_in[16];
  const float* Wq    = (const float*)d_in[17];
  const float* bq    = (const float*)d_in[18];
  const float* Wk    = (const float*)d_in[19];
  const float* bk    = (const float*)d_in[20];
  const float* Wv    = (const float*)d_in[21];
  const float* bv    = (const float*)d_in[22];
  const float* Wo    = (const float*)d_in[23];
  const float* bo    = (const float*)d_in[24];
  const float* att_g = (const float*)d_in[25];
  const float* att_b = (const float*)d_in[26];
  const float* on_g  = (const float*)d_in[27];
  const float* on_b  = (const float*)d_in[28];
  const float* Wp1   = (const float*)d_in[29];
  const float* bp1   = (const float*)d_in[30];
  const float* Wp2   = (const float*)d_in[31];
  const float* bp2   = (const float*)d_in[32];
  float* out = (float*)d_out;

  // ---- workspace layout (floats); never touches d_in ----
  const long SEQF = (long)Bn * Sn * Hn;      // 16,777,216
  const long WHPF = 2L * 256 * G4n;          // 1,048,576 (uint32 slots)
  const long PZF  = 2L * 2 * 64 * 2048;      // 524,288
  const long wsF  = (long)(ws_size / 4);

  float* ws   = (float*)d_ws;
  float* seq  = ws;                  // [B,S,H]
  float* hseq = seq  + SEQF;         // [B,S,H]
  uint32* WhP = (uint32*)(hseq + SEQF);  // [2][256][2048] packed f16 pairs
  float* pz   = hseq + SEQF + WHPF;  // [2][2][64][2048] partials
  int*  flags = (int*)(pz + PZF);    // [2][64] (pad to 1024)
  float* hst  = pz + PZF + 1024L;    // [64][512]
  float* cst  = hst  + 32768L;
  float* qlst = cst  + 32768L;       // [64][512]
  float* ctx  = qlst + 32768L;       // [64][512]
  float* qkh  = ctx  + 32768L;       // [64][8][512]
  float* qbk  = qkh  + 262144L;      // [64][8] (pad to 1024)
  float* uat  = qbk  + 1024L;        // [64][8][512]
  float* ipc  = uat  + 262144L;      // [TCH*64][2048]
  const long baseF = (ipc - ws);

  int TCH = 128;
  while (TCH > 16 && baseF + (long)TCH * 64 * 2048 > wsF) TCH >>= 1;

  wh_pack_k<<<dim3(16, 64, 2), 256, 0, stream>>>(Wh, WhP);
  init_flags_k<<<1, 256, 0, stream>>>(flags);

  const int NCH = Sn / TCH;
  const int MROWS = TCH * 64;
  const int NMCH = (Bn * Sn) / MROWS;

  for (int l = 0; l < 2; ++l) {
    const float* seqin = (l == 0) ? x : seq;
    init_hc_k<<<128, 256, 0, stream>>>(hst, cst);
    for (int c = 0; c < NCH; ++c) {
      const int s0 = c * TCH;
      gemm_ip_k<<<dim3(16, TCH/2), 256, 0, stream>>>(seqin, Wi + (long)l*G4n*Hn, bi + l*G4n, ipc, s0);
      ln_rows_k<<<TCH*64, 256, 0, stream>>>(ipc, g_in + l*G4n, b_in + l*G4n);
      lstm_seq2_k<<<128, 512, 0, stream>>>(WhP + (long)l*256*G4n, bh + l*G4n, ipc,
          g_hid + l*G4n, b_hid + l*G4n, g_cell + l*Hn, b_cell + l*Hn,
          hst, cst, hseq, pz, flags, s0, TCH, l*Sn + s0 + 1);
    }
    // highway, chunked over M; T buffers live in the (dead) ipc region
    float* T1 = ipc;
    float* T2 = ipc + (long)MROWS * 512;
    float* T3 = ipc + 2L * MROWS * 512;
    for (int mc = 0; mc < NMCH; ++mc) {
      const long m0 = (long)mc * MROWS;
      gemm_bias_k<<<dim3(4, MROWS/128), 256, 0, stream>>>(hseq + m0*512, 512, hwWt + (long)l*Hn*Hn, hwbt + l*Hn, T1, 512, 512);
      gemm_bias_k<<<dim3(4, MROWS/128), 256, 0, stream>>>(hseq + m0*512, 512, hwWc + (long)l*Hn*Hn, hwbc + l*Hn, T2, 512, 512);
      gemm_bias_k<<<dim3(4, MROWS/128), 256, 0, stream>>>(hseq + m0*512, 512, hwWh + (long)l*Hn*Hn, hwbh + l*Hn, T3, 512, 512);
      highway_ew_k<<<(MROWS*512)/1024, 256, 0, stream>>>(T1, T2, T3, hseq + m0*512, seq + m0*512, (l == 0) ? 0 : 1);
    }
  }

  // attention on last query row, K/V never materialized
  gemm_m64_k<<<dim3(8, 1), 256, 0, stream>>>(seq + 511L*512, 512L*512, Wq, bq, qlst, 512, 512);
  qkh_k<<<dim3(8, 4), 256, 0, stream>>>(qlst, Wk, bk, qkh, qbk);
  attn2_k<<<dim3(64, 8), 256, 0, stream>>>(seq, qkh, qbk, uat);
  ctxv_k<<<64, 256, 0, stream>>>(uat, Wv, bv, ctx);
  head_k<<<64, 256, 0, stream>>>(ctx, Wo, bo, seq, att_g, att_b, on_g, on_b, Wp1, bp1, Wp2, bp2, out);
}